// Round 4
// baseline (70.612 us; speedup 1.0000x reference)
//
#include <hip/hip_runtime.h>
#include <math.h>

// HeteAttention capsule routing, MI355X — register-resident z + cross-b
// LDS prefetch pipeline (global_load_lds) to keep HBM streaming.
// B=4096, n=1, N=128, F=8 facets, D=16, n_iter=4, C=F*D=128.
// Grid 512 blocks x 256 thr; each block processes NB=8 consecutive b's.
// Lane map: cg = lane&15 owns channels c = cg*8..cg*8+7; lane bit0 = half of
// facet f = cg>>1; kgl = lane>>4; kg = wave*4+kgl owns k = kg*8..kg*8+7.
// z slice = 64 VGPRs. Reductions: DPP quad_perm / mirrors + permlane swaps
// (no DS-pipe shuffles). Softmax max-pass dropped (|logit|<=1).
// Prefetch: wave w's 16KB quarter of z(b+1) streams into zbuf[w*4096..]
// via 16 global_load_lds width=16 — wave-private, so NO barriers for staging;
// b-switch: vmcnt(0) -> ds_read copy -> lgkmcnt(0) -> issue prefetch b+2.

#define CC 128
#define NB 8

typedef unsigned u32x2 __attribute__((ext_vector_type(2)));

template<int CTRL>
__device__ __forceinline__ float dpp_add(float x) {
    int y = __builtin_amdgcn_update_dpp(0, __float_as_int(x), CTRL, 0xF, 0xF, true);
    return x + __int_as_float(y);
}
#define DPP_XOR1 0xB1   // quad_perm [1,0,3,2]
#define DPP_XOR2 0x4E   // quad_perm [2,3,0,1]
#define DPP_HMIR 0x141  // row_half_mirror (lane^7)
#define DPP_MIR  0x140  // row_mirror      (lane^15)

__device__ __forceinline__ float xor16_add(float v) {
    u32x2 r = __builtin_amdgcn_permlane16_swap(__float_as_uint(v), __float_as_uint(v), false, false);
    return __uint_as_float(r.x) + __uint_as_float(r.y);
}
__device__ __forceinline__ float xor32_add(float v) {
    u32x2 r = __builtin_amdgcn_permlane32_swap(__float_as_uint(v), __float_as_uint(v), false, false);
    return __uint_as_float(r.x) + __uint_as_float(r.y);
}
__device__ __forceinline__ float rsq_guard(float s) {
    return __builtin_amdgcn_rsqf(fmaxf(s, 1e-24f));
}

__global__ __launch_bounds__(256, 2)
void hete_routing_kernel(const float* __restrict__ feat,   // [B, 128]
                         const float* __restrict__ mp,     // [B, 128, 128]
                         float* __restrict__ out)          // [B, 128]
{
    __shared__ float zbuf[128 * CC];     // 64 KB prefetch buffer (wave quarters)
    __shared__ float part[2][4][CC];     // 4 KB cross-wave partials (dbuf)

    const int t = threadIdx.x;
    const int wave = t >> 6;
    const int lane = t & 63;
    const int cg = lane & 15;
    const int kgl = lane >> 4;           // 0..3
    const int kg = wave * 4 + kgl;       // 0..15
    const int c0 = cg * 8;
    const int b0 = blockIdx.x * NB;

    float4 za0[8], za1[8];

    // ---- b0: direct global->reg load ----
    {
        const float* zg = mp + (size_t)b0 * (128 * CC);
#pragma unroll
        for (int kk = 0; kk < 8; ++kk) {
            const float* p = zg + (kg * 8 + kk) * CC + c0;
            za0[kk] = *reinterpret_cast<const float4*>(p);
            za1[kk] = *reinterpret_cast<const float4*>(p + 4);
        }
    }
    // ---- issue prefetch of z(b0+1) into this wave's LDS quarter ----
    {
        const float* src = mp + (size_t)(b0 + 1) * (128 * CC) + wave * 4096 + lane * 4;
        float* dst = zbuf + wave * 4096;
#pragma unroll
        for (int j = 0; j < 16; ++j) {
            __builtin_amdgcn_global_load_lds(
                (const __attribute__((address_space(1))) void*)(src + j * 256),
                (__attribute__((address_space(3))) void*)(dst + j * 256),
                16, 0, 0);
        }
    }

#pragma unroll 1
    for (int i = 0; i < NB; ++i) {
        const int b = b0 + i;

        // ---- normalize z per (k, facet): local sumsq + partner-lane half ----
#pragma unroll
        for (int kk = 0; kk < 8; ++kk) {
            float s = za0[kk].x * za0[kk].x + za0[kk].y * za0[kk].y
                    + za0[kk].z * za0[kk].z + za0[kk].w * za0[kk].w
                    + za1[kk].x * za1[kk].x + za1[kk].y * za1[kk].y
                    + za1[kk].z * za1[kk].z + za1[kk].w * za1[kk].w;
            s = dpp_add<DPP_XOR1>(s);
            const float inv = rsq_guard(s);
            za0[kk].x *= inv; za0[kk].y *= inv; za0[kk].z *= inv; za0[kk].w *= inv;
            za1[kk].x *= inv; za1[kk].y *= inv; za1[kk].z *= inv; za1[kk].w *= inv;
        }

        // ---- load + normalize x slice ----
        float xr[8], ur[8];
        {
            const float* p = feat + (size_t)b * CC + c0;
            const float4 a = *reinterpret_cast<const float4*>(p);
            const float4 c = *reinterpret_cast<const float4*>(p + 4);
            xr[0] = a.x; xr[1] = a.y; xr[2] = a.z; xr[3] = a.w;
            xr[4] = c.x; xr[5] = c.y; xr[6] = c.z; xr[7] = c.w;
            float s = 0.f;
#pragma unroll
            for (int j = 0; j < 8; ++j) s += xr[j] * xr[j];
            s = dpp_add<DPP_XOR1>(s);
            const float inv = rsq_guard(s);
#pragma unroll
            for (int j = 0; j < 8; ++j) { xr[j] *= inv; ur[j] = xr[j]; }
        }

        // ---- routing iterations ----
#pragma unroll
        for (int it = 0; it < 4; ++it) {
            // phase1: logits l[k] = z[k,f,:]·u[f,:]
            float w[8];
#pragma unroll
            for (int kk = 0; kk < 8; ++kk) {
                float pl = za0[kk].x * ur[0] + za0[kk].y * ur[1]
                         + za0[kk].z * ur[2] + za0[kk].w * ur[3]
                         + za1[kk].x * ur[4] + za1[kk].y * ur[5]
                         + za1[kk].z * ur[6] + za1[kk].w * ur[7];
                w[kk] = dpp_add<DPP_XOR1>(pl);
            }
            // softmax over facets (lane bits 1..3); |l|<=1 so no max-shift
#pragma unroll
            for (int kk = 0; kk < 8; ++kk) {
                const float e = __expf(w[kk]);
                float su = dpp_add<DPP_XOR2>(e);
                su = dpp_add<DPP_HMIR>(su);
                su = dpp_add<DPP_MIR>(su);
                w[kk] = e * __builtin_amdgcn_rcpf(su);
            }

            // phase2: partial u over this thread's 8 k's, 8 channels
            float pu[8];
#pragma unroll
            for (int j = 0; j < 8; ++j) pu[j] = 0.f;
#pragma unroll
            for (int kk = 0; kk < 8; ++kk) {
                pu[0] += za0[kk].x * w[kk];
                pu[1] += za0[kk].y * w[kk];
                pu[2] += za0[kk].z * w[kk];
                pu[3] += za0[kk].w * w[kk];
                pu[4] += za1[kk].x * w[kk];
                pu[5] += za1[kk].y * w[kk];
                pu[6] += za1[kk].z * w[kk];
                pu[7] += za1[kk].w * w[kk];
            }
            // reduce over kgl (lane bits 4,5) via permlane swaps (VALU)
#pragma unroll
            for (int j = 0; j < 8; ++j) {
                pu[j] = xor16_add(pu[j]);
                pu[j] = xor32_add(pu[j]);
            }
            // cross-wave reduce via tiny LDS buffer
            if (kgl == 0) {
                float* dst = &part[it & 1][wave][c0];
                *reinterpret_cast<float4*>(dst)     = make_float4(pu[0], pu[1], pu[2], pu[3]);
                *reinterpret_cast<float4*>(dst + 4) = make_float4(pu[4], pu[5], pu[6], pu[7]);
            }
            __syncthreads();

            float un[8];
#pragma unroll
            for (int j = 0; j < 8; ++j) un[j] = xr[j];
#pragma unroll
            for (int wv = 0; wv < 4; ++wv) {
                const float* src = &part[it & 1][wv][c0];
                const float4 a = *reinterpret_cast<const float4*>(src);
                const float4 c = *reinterpret_cast<const float4*>(src + 4);
                un[0] += a.x; un[1] += a.y; un[2] += a.z; un[3] += a.w;
                un[4] += c.x; un[5] += c.y; un[6] += c.z; un[7] += c.w;
            }

            if (it < 3) {
                float s = 0.f;
#pragma unroll
                for (int j = 0; j < 8; ++j) s += un[j] * un[j];
                s = dpp_add<DPP_XOR1>(s);
                const float inv = rsq_guard(s);
#pragma unroll
                for (int j = 0; j < 8; ++j) ur[j] = un[j] * inv;
            } else if (wave == 0 && kgl == 0) {
                float* dst = out + (size_t)b * CC + c0;
                *reinterpret_cast<float4*>(dst)     = make_float4(un[0], un[1], un[2], un[3]);
                *reinterpret_cast<float4*>(dst + 4) = make_float4(un[4], un[5], un[6], un[7]);
            }
        }

        // ---- b-switch: land prefetched tile, copy to regs, refill pipe ----
        if (i + 1 < NB) {
            asm volatile("s_waitcnt vmcnt(0)" ::: "memory");   // prefetch landed
#pragma unroll
            for (int kk = 0; kk < 8; ++kk) {
                const float* p = zbuf + (kg * 8 + kk) * CC + c0;   // wave-private rows
                za0[kk] = *reinterpret_cast<const float4*>(p);
                za1[kk] = *reinterpret_cast<const float4*>(p + 4);
            }
            asm volatile("s_waitcnt lgkmcnt(0)" ::: "memory");  // reads done before overwrite
            if (i + 2 < NB) {
                const float* src = mp + (size_t)(b0 + i + 2) * (128 * CC) + wave * 4096 + lane * 4;
                float* dst = zbuf + wave * 4096;
#pragma unroll
                for (int j = 0; j < 16; ++j) {
                    __builtin_amdgcn_global_load_lds(
                        (const __attribute__((address_space(1))) void*)(src + j * 256),
                        (__attribute__((address_space(3))) void*)(dst + j * 256),
                        16, 0, 0);
                }
            }
        }
    }
}

extern "C" void kernel_launch(void* const* d_in, const int* in_sizes, int n_in,
                              void* d_out, int out_size, void* d_ws, size_t ws_size,
                              hipStream_t stream) {
    const float* feat = (const float*)d_in[0];   // features [B,1,128] fp32
    const float* mp   = (const float*)d_in[1];   // metapath [B,1,128,128] fp32
    float* out = (float*)d_out;                  // [B,128] fp32
    const int B = in_sizes[0] / CC;              // 4096
    hete_routing_kernel<<<B / NB, 256, 0, stream>>>(feat, mp, out);
}

// Round 5
// 54.853 us; speedup vs baseline: 1.2873x; 1.2873x over previous
//
#include <hip/hip_runtime.h>
#include <math.h>

// HeteAttention capsule routing, MI355X — register-resident z, packed-FP32
// (v_pk_fma_f32) math, permlane cross-wave combine, register prefetch of the
// next batch element (grid-stride NB=4).
// B=4096, n=1, N=128, F=8 facets, D=16, n_iter=4, C=F*D=128.
// Grid 1024 blocks x 256 thr (4 blocks/CU); each block does NB=4 b's.
// Lane map: cg = lane&15 owns channels c = cg*8..cg*8+7 (as 4 f32x2); lane
// bit0 = half of facet f = cg>>1; kgl = lane>>4; kg = wave*4+kgl owns
// k = kg*8..kg*8+7. z slice = 64 VGPRs (f32x2[8][4]).
// Reductions: DPP quad_perm/mirrors (bit0 + softmax bits1..3), permlane
// 16/32 swaps (kgl bits + cross-wave partial exchange). Softmax max-pass
// dropped (|logit|<=1, shift-invariant); exp via exp2 with log2e folded
// into ur. Prefetch: after it=3 phase2, za is dead -> issue b+1's 16
// global_load_dwordx4 into za; plain register loads cross s_barrier with
// no vmcnt drain (unlike global_load_lds, R4's failure).

#define CC 128
#define NB 4
#define LOG2E 1.44269504088896340736f

typedef float f32x2 __attribute__((ext_vector_type(2)));
typedef unsigned u32x2 __attribute__((ext_vector_type(2)));

template<int CTRL>
__device__ __forceinline__ float dpp_add(float x) {
    int y = __builtin_amdgcn_update_dpp(0, __float_as_int(x), CTRL, 0xF, 0xF, true);
    return x + __int_as_float(y);
}
#define DPP_XOR1 0xB1   // quad_perm [1,0,3,2]
#define DPP_XOR2 0x4E   // quad_perm [2,3,0,1]
#define DPP_HMIR 0x141  // row_half_mirror (^7; ^4 given uniform low bits)
#define DPP_MIR  0x140  // row_mirror      (^15; ^8 given uniform low bits)

__device__ __forceinline__ f32x2 xor16_add2(f32x2 v) {
    u32x2 r0 = __builtin_amdgcn_permlane16_swap(__float_as_uint(v.x), __float_as_uint(v.x), false, false);
    u32x2 r1 = __builtin_amdgcn_permlane16_swap(__float_as_uint(v.y), __float_as_uint(v.y), false, false);
    f32x2 o;
    o.x = __uint_as_float(r0.x) + __uint_as_float(r0.y);
    o.y = __uint_as_float(r1.x) + __uint_as_float(r1.y);
    return o;
}
__device__ __forceinline__ f32x2 xor32_add2(f32x2 v) {
    u32x2 r0 = __builtin_amdgcn_permlane32_swap(__float_as_uint(v.x), __float_as_uint(v.x), false, false);
    u32x2 r1 = __builtin_amdgcn_permlane32_swap(__float_as_uint(v.y), __float_as_uint(v.y), false, false);
    f32x2 o;
    o.x = __uint_as_float(r0.x) + __uint_as_float(r0.y);
    o.y = __uint_as_float(r1.x) + __uint_as_float(r1.y);
    return o;
}
__device__ __forceinline__ float rsq_guard(float s) {
    return __builtin_amdgcn_rsqf(fmaxf(s, 1e-24f));
}

// 16 dwordx4 loads, one SGPR-ish base + small const offsets.
__device__ __forceinline__ void load_z(f32x2 za[8][4], const float* base) {
#pragma unroll
    for (int kk = 0; kk < 8; ++kk) {
        const float4 A = *reinterpret_cast<const float4*>(base + kk * CC);
        const float4 Bv = *reinterpret_cast<const float4*>(base + kk * CC + 4);
        za[kk][0] = f32x2{A.x, A.y};
        za[kk][1] = f32x2{A.z, A.w};
        za[kk][2] = f32x2{Bv.x, Bv.y};
        za[kk][3] = f32x2{Bv.z, Bv.w};
    }
}

__global__ __launch_bounds__(256, 4)
void hete_routing_kernel(const float* __restrict__ feat,   // [B, 128]
                         const float* __restrict__ mp,     // [B, 128, 128]
                         float* __restrict__ out)          // [B, 128]
{
    __shared__ float part[2][4][CC];     // 4 KB cross-wave partials (dbuf)

    const int t = threadIdx.x;
    const int wave = t >> 6;
    const int lane = t & 63;
    const int cg = lane & 15;
    const int kgl = lane >> 4;           // 0..3
    const int kg = wave * 4 + kgl;       // 0..15
    const int c0 = cg * 8;
    const int b0 = blockIdx.x * NB;

    f32x2 za[8][4];
    const float* zb = mp + (size_t)b0 * (128 * CC) + kg * 8 * CC + c0;
    load_z(za, zb);                      // b0: direct global->reg

#pragma unroll 1
    for (int i = 0; i < NB; ++i) {
        const int b = b0 + i;

        // ---- load x slice (issues while z-normalize runs) ----
        const float* px = feat + (size_t)b * CC + c0;
        const float4 xa = *reinterpret_cast<const float4*>(px);
        const float4 xc = *reinterpret_cast<const float4*>(px + 4);

        // ---- normalize z per (k, facet): pk sumsq + partner-lane half ----
#pragma unroll
        for (int kk = 0; kk < 8; ++kk) {
            f32x2 s2 = za[kk][0] * za[kk][0];
            s2 += za[kk][1] * za[kk][1];
            s2 += za[kk][2] * za[kk][2];
            s2 += za[kk][3] * za[kk][3];
            float s = s2.x + s2.y;
            s = dpp_add<DPP_XOR1>(s);
            const float inv = rsq_guard(s);
            const f32x2 inv2 = {inv, inv};
            za[kk][0] *= inv2; za[kk][1] *= inv2;
            za[kk][2] *= inv2; za[kk][3] *= inv2;
        }

        // ---- normalize x; ur = x_hat * log2e (folds exp->exp2 scale) ----
        f32x2 xr[4], ur[4];
        {
            xr[0] = f32x2{xa.x, xa.y}; xr[1] = f32x2{xa.z, xa.w};
            xr[2] = f32x2{xc.x, xc.y}; xr[3] = f32x2{xc.z, xc.w};
            f32x2 s2 = xr[0] * xr[0];
            s2 += xr[1] * xr[1];
            s2 += xr[2] * xr[2];
            s2 += xr[3] * xr[3];
            float s = s2.x + s2.y;
            s = dpp_add<DPP_XOR1>(s);
            const float inv = rsq_guard(s);
            const f32x2 inv2 = {inv, inv};
            const f32x2 invs = {inv * LOG2E, inv * LOG2E};
#pragma unroll
            for (int j = 0; j < 4; ++j) { ur[j] = xr[j] * invs; xr[j] *= inv2; }
        }

        // ---- routing iterations ----
#pragma unroll
        for (int it = 0; it < 4; ++it) {
            const int p = it & 1;
            // phase1: logits (pre-scaled by log2e) via pk_fma + DPP pair-sum
            float w[8];
#pragma unroll
            for (int kk = 0; kk < 8; ++kk) {
                f32x2 acc = za[kk][0] * ur[0];
                acc += za[kk][1] * ur[1];
                acc += za[kk][2] * ur[2];
                acc += za[kk][3] * ur[3];
                w[kk] = dpp_add<DPP_XOR1>(acc.x + acc.y);
            }
            // softmax over facets (lane bits 1..3); no max-shift (|l|<=log2e)
#pragma unroll
            for (int kk = 0; kk < 8; ++kk) {
                const float e = __builtin_amdgcn_exp2f(w[kk]);
                float su = dpp_add<DPP_XOR2>(e);
                su = dpp_add<DPP_HMIR>(su);
                su = dpp_add<DPP_MIR>(su);
                w[kk] = e * __builtin_amdgcn_rcpf(su);
            }

            // phase2: weighted z sum over this thread's 8 k's (pk_fma)
            f32x2 pu[4] = {f32x2{0.f,0.f}, f32x2{0.f,0.f}, f32x2{0.f,0.f}, f32x2{0.f,0.f}};
#pragma unroll
            for (int kk = 0; kk < 8; ++kk) {
                const f32x2 ws = {w[kk], w[kk]};
                pu[0] += za[kk][0] * ws;
                pu[1] += za[kk][1] * ws;
                pu[2] += za[kk][2] * ws;
                pu[3] += za[kk][3] * ws;
            }
            // k-reduce over kgl (lane bits 4,5) via permlane swaps (VALU)
#pragma unroll
            for (int j = 0; j < 4; ++j) {
                pu[j] = xor16_add2(pu[j]);
                pu[j] = xor32_add2(pu[j]);
            }
            if (kgl == 0) {
                float* dst = &part[p][wave][c0];
                *reinterpret_cast<float4*>(dst)     = make_float4(pu[0].x, pu[0].y, pu[1].x, pu[1].y);
                *reinterpret_cast<float4*>(dst + 4) = make_float4(pu[2].x, pu[2].y, pu[3].x, pu[3].y);
            }
            __syncthreads();

            // register prefetch of b+1's z: za is dead after phase2, plain
            // register loads cross barriers with no vmcnt drain.
            if (it == 3 && i + 1 < NB) {
                load_z(za, zb + (size_t)(i + 1) * (128 * CC));
            }

            // combine: each kgl-group reads ONE wave-partial, exchange via
            // permlane16/32 to sum the 4, then add x.
            f32x2 pw[4];
            {
                const float* src = &part[p][kgl][c0];
                const float4 A = *reinterpret_cast<const float4*>(src);
                const float4 Cv = *reinterpret_cast<const float4*>(src + 4);
                pw[0] = f32x2{A.x, A.y}; pw[1] = f32x2{A.z, A.w};
                pw[2] = f32x2{Cv.x, Cv.y}; pw[3] = f32x2{Cv.z, Cv.w};
            }
#pragma unroll
            for (int j = 0; j < 4; ++j) {
                pw[j] = xor16_add2(pw[j]);
                pw[j] = xor32_add2(pw[j]);
            }
            f32x2 un[4];
#pragma unroll
            for (int j = 0; j < 4; ++j) un[j] = xr[j] + pw[j];

            if (it < 3) {
                f32x2 s2 = un[0] * un[0];
                s2 += un[1] * un[1];
                s2 += un[2] * un[2];
                s2 += un[3] * un[3];
                float s = s2.x + s2.y;
                s = dpp_add<DPP_XOR1>(s);
                const float invs = rsq_guard(s) * LOG2E;
                const f32x2 iv = {invs, invs};
#pragma unroll
                for (int j = 0; j < 4; ++j) ur[j] = un[j] * iv;
            } else if (wave == 0 && kgl == 0) {
                float* dst = out + (size_t)b * CC + c0;
                *reinterpret_cast<float4*>(dst)     = make_float4(un[0].x, un[0].y, un[1].x, un[1].y);
                *reinterpret_cast<float4*>(dst + 4) = make_float4(un[2].x, un[2].y, un[3].x, un[3].y);
            }
        }
    }
}

extern "C" void kernel_launch(void* const* d_in, const int* in_sizes, int n_in,
                              void* d_out, int out_size, void* d_ws, size_t ws_size,
                              hipStream_t stream) {
    const float* feat = (const float*)d_in[0];   // features [B,1,128] fp32
    const float* mp   = (const float*)d_in[1];   // metapath [B,1,128,128] fp32
    float* out = (float*)d_out;                  // [B,128] fp32
    const int B = in_sizes[0] / CC;              // 4096
    hete_routing_kernel<<<B / NB, 256, 0, stream>>>(feat, mp, out);
}